// Round 1
// 367.062 us; speedup vs baseline: 1.2325x; 1.2325x over previous
//
#include <hip/hip_runtime.h>

// MipMap: out = relu(interp(G)+b1)@W2 + b2, G = sum_l b_l * blur_l(base@W1).
// Blur acts on spatial axes, W1 on the feature axis -> commute; interp linear.
// R13 PASSED 452 us, kblur 246 us at 46% HBM with 421MB FETCH / 475MB WRITE
// vs 130/34 MB logical: (y,x,f) layout gives kblur 8B-per-64B-line accesses.
// R14: feature-pair-major planes Gp[fp][y][x][2] for the blur pipeline.
//  - kgemm epilogue stages through LDS (stride-132 pad) -> coalesced f32x4
//    plane writes of G0p.
//  - kblur reads/writes planes (fp = blockIdx.z), fully coalesced; blur math
//    byte-identical to R12/R13.
//  - new ktrans: planes -> (y,x,f) via LDS tile, coalesced both sides, so
//    kgather keeps its 512B coalesced corner-row reads. G reuses G0p region.
// Style: no cstdint, no unions, no templates (R9's build-fix delta).

typedef short short8 __attribute__((ext_vector_type(8)));
typedef float f32x4 __attribute__((ext_vector_type(4)));

__device__ __forceinline__ unsigned short f2bfbits(float f) {
    unsigned int x = __float_as_uint(f);
    x += 0x7fffu + ((x >> 16) & 1u);   // round-to-nearest-even
    return (unsigned short)(x >> 16);
}

__global__ void kcoef(const float* blev, float* coef) {
    // coef[0..63] horiz taps, coef[64..127] vert taps * b_level, coef[128] b0
    if (blockIdx.x != 0 || threadIdx.x != 0) return;
    int offs[6];
    offs[0] = 0; offs[1] = 0; offs[2] = 2; offs[3] = 6; offs[4] = 14; offs[5] = 30;
    for (int l = 1; l <= 5; l++) {
        int s = 1 << l;
        int off = offs[l];
        float sum = 0.0f;
        for (int m = 0; m < s; m++) {
            float x = ((float)m - (float)(s - 1) * 0.5f) / ((float)s * 0.5f);
            float w = expf(-0.5f * x * x);
            coef[off + m] = w;
            sum += w;
        }
        float bl = blev[l];
        for (int m = 0; m < s; m++) {
            float w = coef[off + m] / sum;
            coef[off + m] = w;
            coef[64 + off + m] = w * bl;
        }
    }
    coef[128] = blev[0];
}

// pack base (f32, 8.4M) -> bf16, two elements per thread as one u32 store
__global__ void kconvA(const float* base, unsigned int* Abf2, int n2) {
    int i = blockIdx.x * 256 + threadIdx.x;
    if (i >= n2) return;
    unsigned int lo = f2bfbits(base[2 * i]);
    unsigned int hi = f2bfbits(base[2 * i + 1]);
    Abf2[i] = (hi << 16) | lo;
}

// W1 (k,n) f32 -> W1T (n,k) bf16 so B-fragments are contiguous 16 B loads
__global__ void kconvW(const float* W1, unsigned short* W1T) {
    int i = blockIdx.x * 256 + threadIdx.x;   // 16384
    int k = i >> 7;
    int n = i & 127;
    W1T[n * 128 + k] = f2bfbits(W1[i]);
}

// MFMA GEMM: G0p(64 planes of 65536x2) = base_bf16 @ W1_bf16, plane layout.
// Wave = 16 rows x 128 cols (8 tiles of 16x16, K-loop 4x32). Block = 4
// waves = 64 rows. A-frag: A[m=lane&15][k=quad*8+j]; B-frag from W1T row n;
// D: m_off=quad*4+r, n=c*16+(lane&15) (guide-verified m89/m91). Epilogue
// stages the 64x128 block tile in LDS (stride 132: conflict-pad, 16B-align)
// then writes plane-major with coalesced f32x4 stores.
__global__ void kgemm(const unsigned short* Abf, const unsigned short* W1T,
                      float* G0p) {
    __shared__ float stg[64 * 132];
    int tid = threadIdx.x;
    int wv = tid >> 6;
    int lane = tid & 63;
    int colI = lane & 15;
    int quad = lane >> 4;
    int m0 = blockIdx.x * 64 + wv * 16;
    f32x4 zero = {0.0f, 0.0f, 0.0f, 0.0f};
    f32x4 acc0 = zero; f32x4 acc1 = zero; f32x4 acc2 = zero; f32x4 acc3 = zero;
    f32x4 acc4 = zero; f32x4 acc5 = zero; f32x4 acc6 = zero; f32x4 acc7 = zero;
    for (int kc = 0; kc < 4; kc++) {
        int k0 = kc * 32 + quad * 8;
        short8 a = *(const short8*)(Abf + (size_t)(m0 + colI) * 128 + k0);
        const unsigned short* wb = W1T + (size_t)colI * 128 + k0;
        short8 b0 = *(const short8*)(wb + 0 * 16 * 128);
        short8 b1 = *(const short8*)(wb + 1 * 16 * 128);
        short8 b2 = *(const short8*)(wb + 2 * 16 * 128);
        short8 b3 = *(const short8*)(wb + 3 * 16 * 128);
        short8 b4 = *(const short8*)(wb + 4 * 16 * 128);
        short8 b5 = *(const short8*)(wb + 5 * 16 * 128);
        short8 b6 = *(const short8*)(wb + 6 * 16 * 128);
        short8 b7 = *(const short8*)(wb + 7 * 16 * 128);
        acc0 = __builtin_amdgcn_mfma_f32_16x16x32_bf16(a, b0, acc0, 0, 0, 0);
        acc1 = __builtin_amdgcn_mfma_f32_16x16x32_bf16(a, b1, acc1, 0, 0, 0);
        acc2 = __builtin_amdgcn_mfma_f32_16x16x32_bf16(a, b2, acc2, 0, 0, 0);
        acc3 = __builtin_amdgcn_mfma_f32_16x16x32_bf16(a, b3, acc3, 0, 0, 0);
        acc4 = __builtin_amdgcn_mfma_f32_16x16x32_bf16(a, b4, acc4, 0, 0, 0);
        acc5 = __builtin_amdgcn_mfma_f32_16x16x32_bf16(a, b5, acc5, 0, 0, 0);
        acc6 = __builtin_amdgcn_mfma_f32_16x16x32_bf16(a, b6, acc6, 0, 0, 0);
        acc7 = __builtin_amdgcn_mfma_f32_16x16x32_bf16(a, b7, acc7, 0, 0, 0);
    }
    // stage to LDS: stg[(n>>1)*132 + m_local*2 + (n&1)], m_local in [0,64)
    int mlb = (wv * 16 + quad * 4) * 2;
#define STG(c, A) { int n = c * 16 + colI; \
    float* p = stg + (n >> 1) * 132 + mlb + (n & 1); \
    p[0] = A[0]; p[2] = A[1]; p[4] = A[2]; p[6] = A[3]; }
    STG(0, acc0) STG(1, acc1) STG(2, acc2) STG(3, acc3)
    STG(4, acc4) STG(5, acc5) STG(6, acc6) STG(7, acc7)
#undef STG
    __syncthreads();
    size_t m0b2 = (size_t)blockIdx.x * 128;   // m0_block * 2
    for (int j = tid; j < 2048; j += 256) {
        int fp = j >> 5;
        int q = (j & 31) * 4;
        f32x4 v = *(const f32x4*)&stg[fp * 132 + q];
        *(f32x4*)(G0p + (size_t)fp * 131072 + m0b2 + q) = v;
    }
}

// one gaussian level: H pass (x) into H_t, V pass (y) accumulates into acc.
__device__ void blur_level(const float* in_t, float* H_t,
                           const float* kh_s, const float* kv_s,
                           int tid, float* acc, int S, int off) {
    int half = S / 2;
    int nrows = 31 + S;
    for (int g = tid; g < nrows * 8; g += 512) {
        int yy = (16 - half) + (g >> 3);
        int xg = g & 7;
        float a00 = 0.0f, a01 = 0.0f, a10 = 0.0f, a11 = 0.0f;
        float a20 = 0.0f, a21 = 0.0f, a30 = 0.0f, a31 = 0.0f;
        int cb = xg * 4 + 16 - half;
        for (int t = 0; t < S + 3; t++) {
            float v0 = in_t[(yy * 66 + cb + t) * 2 + 0];
            float v1 = in_t[(yy * 66 + cb + t) * 2 + 1];
            if (t < S)              { float k = kh_s[off + t];     a00 += k * v0; a01 += k * v1; }
            if (t >= 1 && t - 1 < S){ float k = kh_s[off + t - 1]; a10 += k * v0; a11 += k * v1; }
            if (t >= 2 && t - 2 < S){ float k = kh_s[off + t - 2]; a20 += k * v0; a21 += k * v1; }
            if (t >= 3 && t - 3 < S){ float k = kh_s[off + t - 3]; a30 += k * v0; a31 += k * v1; }
        }
        int hb = (yy * 33 + xg * 4) * 2;
        H_t[hb + 0] = a00; H_t[hb + 1] = a01;
        H_t[hb + 2] = a10; H_t[hb + 3] = a11;
        H_t[hb + 4] = a20; H_t[hb + 5] = a21;
        H_t[hb + 6] = a30; H_t[hb + 7] = a31;
    }
    __syncthreads();
    int xl = tid & 31;
    int ygrp = tid >> 5;
    int ybase = ygrp * 2 + 16 - half;
    for (int t = 0; t <= S; t++) {
        float h0 = H_t[((ybase + t) * 33 + xl) * 2 + 0];
        float h1 = H_t[((ybase + t) * 33 + xl) * 2 + 1];
        if (t < S)  { float k = kv_s[off + t];     acc[0] += k * h0; acc[1] += k * h1; }
        if (t >= 1) { float k = kv_s[off + t - 1]; acc[2] += k * h0; acc[3] += k * h1; }
    }
    __syncthreads();
}

// fused 6-level blur: 32x32 spatial tile x one feature-pair plane, halo 16
// each side. Plane layout -> all global accesses contiguous along x.
__global__ void kblur(const float* G0p, const float* coef, float* Gb) {
    __shared__ float in_t[63 * 66 * 2];
    __shared__ float H_t[63 * 33 * 2];
    __shared__ float kh_s[64];
    __shared__ float kv_s[64];
    __shared__ float b0s[1];
    int tid = threadIdx.x;
    int x0 = blockIdx.x * 32;
    int y0 = blockIdx.y * 32;
    int fp = blockIdx.z;
    const float* Pin = G0p + (size_t)fp * 131072;
    float* Pout = Gb + (size_t)fp * 131072;
    if (tid < 64) { kh_s[tid] = coef[tid]; kv_s[tid] = coef[64 + tid]; }
    if (tid == 64) b0s[0] = coef[128];
    for (int i = tid; i < 63 * 63; i += 512) {
        int yy = i / 63;
        int xx = i - yy * 63;
        int gy = y0 + yy - 16; if (gy < 0) gy = -gy; if (gy > 255) gy = 510 - gy;
        int gx = x0 + xx - 16; if (gx < 0) gx = -gx; if (gx > 255) gx = 510 - gx;
        const float* src = Pin + (size_t)(gy * 256 + gx) * 2;
        in_t[(yy * 66 + xx) * 2 + 0] = src[0];
        in_t[(yy * 66 + xx) * 2 + 1] = src[1];
    }
    __syncthreads();
    int xl = tid & 31;
    int ygrp = tid >> 5;
    float acc[4];
    float b0 = b0s[0];
    acc[0] = b0 * in_t[((ygrp * 2 + 16) * 66 + xl + 16) * 2 + 0];
    acc[1] = b0 * in_t[((ygrp * 2 + 16) * 66 + xl + 16) * 2 + 1];
    acc[2] = b0 * in_t[((ygrp * 2 + 17) * 66 + xl + 16) * 2 + 0];
    acc[3] = b0 * in_t[((ygrp * 2 + 17) * 66 + xl + 16) * 2 + 1];
    blur_level(in_t, H_t, kh_s, kv_s, tid, acc, 2, 0);
    blur_level(in_t, H_t, kh_s, kv_s, tid, acc, 4, 2);
    blur_level(in_t, H_t, kh_s, kv_s, tid, acc, 8, 6);
    blur_level(in_t, H_t, kh_s, kv_s, tid, acc, 16, 14);
    blur_level(in_t, H_t, kh_s, kv_s, tid, acc, 32, 30);
    for (int i = 0; i < 2; i++) {
        int gy = y0 + ygrp * 2 + i;
        int gx = x0 + xl;
        float* dst = Pout + (size_t)(gy * 256 + gx) * 2;
        dst[0] = acc[i * 2 + 0];
        dst[1] = acc[i * 2 + 1];
    }
}

// planes (64 x 65536 x 2) -> (y,x,f=128) for the gather. LDS tile of 32 x
// positions x 128 features at one y; coalesced 256B reads / 512B writes.
__global__ void ktrans(const float* Gb, float* G) {
    __shared__ float lds[32 * 132];
    int t = threadIdx.x;
    int x0 = blockIdx.x * 32;
    int y = blockIdx.y;
    size_t mbase = (size_t)(y * 256 + x0) * 2;
    int fp = t >> 2;
    int j0 = (t & 3) * 16;
    const float* src = Gb + (size_t)fp * 131072 + mbase + j0;
    for (int k4 = 0; k4 < 4; k4++) {
        f32x4 v = *(const f32x4*)(src + k4 * 4);
        for (int u = 0; u < 4; u++) {
            int j = j0 + k4 * 4 + u;
            lds[(j >> 1) * 132 + fp * 2 + (j & 1)] = v[u];
        }
    }
    __syncthreads();
    int xl = t >> 3;
    int f0 = (t & 7) * 16;
    float* dst = G + (size_t)(y * 256 + x0 + xl) * 128 + f0;
    for (int k = 0; k < 16; k += 4) {
        f32x4 v = *(const f32x4*)&lds[xl * 132 + f0 + k];
        *(f32x4*)(dst + k) = v;
    }
}

// wave-per-point gather: lane L owns features {2L, 2L+1}; coalesced 512 B
// corner-row reads; shfl_xor tree reduces 4 outputs; writes out (+b2).
__global__ void kgather(const float* pt, const float* G, const float* b1,
                        const float* W2, const float* b2, float* out) {
    int lane = threadIdx.x & 63;
    int wv = threadIdx.x >> 6;
    int i = blockIdx.x * 4 + wv;
    float py = pt[2 * i];
    float px = pt[2 * i + 1];
    float ay = (py + 1.0f) * 0.5f * 255.0f;
    float ax = (px + 1.0f) * 0.5f * 255.0f;
    int iy = (int)ay;
    int ix = (int)ax;
    if (iy < 0) iy = 0;
    if (iy > 255) iy = 255;
    if (ix < 0) ix = 0;
    if (ix > 255) ix = 255;
    float fy = ay - (float)iy;
    float fx = ax - (float)ix;
    int iy1 = iy + 1; if (iy1 > 255) iy1 = 255;
    int ix1 = ix + 1; if (ix1 > 255) ix1 = 255;
    float w00 = (1.0f - fy) * (1.0f - fx);
    float w01 = (1.0f - fy) * fx;
    float w10 = fy * (1.0f - fx);
    float w11 = fy * fx;
    int f = lane * 2;
    const float* r00 = G + (size_t)(iy * 256 + ix) * 128 + f;
    const float* r01 = G + (size_t)(iy * 256 + ix1) * 128 + f;
    const float* r10 = G + (size_t)(iy1 * 256 + ix) * 128 + f;
    const float* r11 = G + (size_t)(iy1 * 256 + ix1) * 128 + f;
    float v0 = w00 * r00[0] + w01 * r01[0] + w10 * r10[0] + w11 * r11[0] + b1[f];
    float v1 = w00 * r00[1] + w01 * r01[1] + w10 * r10[1] + w11 * r11[1] + b1[f + 1];
    if (v0 < 0.0f) v0 = 0.0f;
    if (v1 < 0.0f) v1 = 0.0f;
    float o0 = v0 * W2[f * 4 + 0] + v1 * W2[f * 4 + 4];
    float o1 = v0 * W2[f * 4 + 1] + v1 * W2[f * 4 + 5];
    float o2 = v0 * W2[f * 4 + 2] + v1 * W2[f * 4 + 6];
    float o3 = v0 * W2[f * 4 + 3] + v1 * W2[f * 4 + 7];
    for (int m = 32; m >= 1; m >>= 1) {
        o0 += __shfl_xor(o0, m);
        o1 += __shfl_xor(o1, m);
        o2 += __shfl_xor(o2, m);
        o3 += __shfl_xor(o3, m);
    }
    if (lane == 0) {
        out[4 * i + 0] = o0 + b2[0];
        out[4 * i + 1] = o1 + b2[1];
        out[4 * i + 2] = o2 + b2[2];
        out[4 * i + 3] = o3 + b2[3];
    }
}

extern "C" void kernel_launch(void* const* d_in, const int* in_sizes, int n_in,
                              void* d_out, int out_size, void* d_ws, size_t ws_size,
                              hipStream_t stream) {
    const float* pt   = (const float*)d_in[0];
    const float* base = (const float*)d_in[1];
    const float* blev = (const float*)d_in[2];
    const float* W1   = (const float*)d_in[3];
    const float* b1   = (const float*)d_in[4];
    const float* W2   = (const float*)d_in[5];
    const float* b2   = (const float*)d_in[6];
    if (n_in == 7) {
        for (int i = 0; i < 7; i++) {
            int sz = in_sizes[i];
            if (sz == 524288)       pt   = (const float*)d_in[i];
            else if (sz == 8388608) base = (const float*)d_in[i];
            else if (sz == 6)       blev = (const float*)d_in[i];
            else if (sz == 16384)   W1   = (const float*)d_in[i];
            else if (sz == 128)     b1   = (const float*)d_in[i];
            else if (sz == 512)     W2   = (const float*)d_in[i];
            else if (sz == 4)       b2   = (const float*)d_in[i];
        }
    }
    float* out = (float*)d_out;
    char* ws = (char*)d_ws;

    // ws: coef 1 KB | Abf 16 MiB | W1T 32 KB | G0p 32 MiB | Gb 32 MiB.
    // After kblur, G0p region is dead -> ktrans writes final (y,x,f) G there.
    size_t off0 = 1024;
    size_t off1 = off0 + 16777216;
    size_t off2 = off1 + 65536;
    size_t off3 = off2 + 33554432;
    size_t need = off3 + 33554432;
    if (ws_size < need) return;

    float* coef = (float*)ws;
    unsigned short* Abf = (unsigned short*)(ws + off0);
    unsigned short* W1T = (unsigned short*)(ws + off1);
    float* G0p = (float*)(ws + off2);       // plane-major GEMM output
    float* Gb  = (float*)(ws + off3);       // plane-major blurred
    float* G   = (float*)(ws + off2);       // (y,x,f) final, reuses G0p

    kcoef<<<1, 64, 0, stream>>>(blev, coef);
    kconvA<<<16384, 256, 0, stream>>>(base, (unsigned int*)Abf, 4194304);
    kconvW<<<64, 256, 0, stream>>>(W1, W1T);
    kgemm<<<1024, 256, 0, stream>>>(Abf, W1T, G0p);
    dim3 gb(8, 8, 64);
    kblur<<<gb, 512, 0, stream>>>(G0p, coef, Gb);
    ktrans<<<dim3(8, 256), 256, 0, stream>>>(Gb, G);
    kgather<<<65536, 256, 0, stream>>>(pt, G, b1, W2, b2, out);
}